// Round 1
// baseline (223.437 us; speedup 1.0000x reference)
//
#include <hip/hip_runtime.h>
#include <math.h>

#define NUM_K   1024
#define CDIM    64
#define HW      1024          // 32*32
#define NROWS   65536         // 64*1024
#define CHUNK   128           // codes staged in LDS per iteration
#define RPB     64            // rows per block
#define NBLK    (NROWS / RPB) // 1024

// numpy pairwise_sum order for n=64 contiguous fp32 (8 stride-8 chains,
// ((r0+r1)+(r2+r3))+((r4+r5)+(r6+r7))), squares rounded separately (no FMA).
__device__ __forceinline__ float np_sumsq64(const float* a) {
#pragma clang fp contract(off)
  float r0 = a[0]*a[0], r1 = a[1]*a[1], r2 = a[2]*a[2], r3 = a[3]*a[3];
  float r4 = a[4]*a[4], r5 = a[5]*a[5], r6 = a[6]*a[6], r7 = a[7]*a[7];
#pragma unroll
  for (int i = 8; i < 64; i += 8) {
    r0 += a[i+0]*a[i+0]; r1 += a[i+1]*a[i+1];
    r2 += a[i+2]*a[i+2]; r3 += a[i+3]*a[i+3];
    r4 += a[i+4]*a[i+4]; r5 += a[i+5]*a[i+5];
    r6 += a[i+6]*a[i+6]; r7 += a[i+7]*a[i+7];
  }
  return ((r0+r1)+(r2+r3))+((r4+r5)+(r6+r7));
}

__global__ void vq_norms(const float* __restrict__ emb, float* __restrict__ norms) {
  int k = blockIdx.x * blockDim.x + threadIdx.x;
  if (k < NUM_K) norms[k] = np_sumsq64(emb + k * CDIM);
}

__global__ __launch_bounds__(256, 4)
void vq_main(const float* __restrict__ xin, const float* __restrict__ emb,
             const float* __restrict__ norms, float* __restrict__ out0,
             float* __restrict__ out_idx, double* __restrict__ partials,
             unsigned int* __restrict__ counts)
{
  __shared__ float e_s[CHUNK * CDIM];       // 32 KB
  __shared__ float nk_s[CHUNK];             // 512 B
  __shared__ unsigned int hist_s[NUM_K];    // 4 KB
  __shared__ float dmin_s[3 * RPB];
  __shared__ int   kmin_s[3 * RPB];

  const int t  = threadIdx.x;
  const int p  = t >> 6;        // k-parity (wave id), k ≡ p (mod 4)
  const int r  = t & 63;        // row within block
  const int n  = blockIdx.x * RPB + r;
  const int b  = n >> 10;
  const int hw = n & (HW - 1);

  for (int i = t; i < NUM_K; i += 256) hist_s[i] = 0;

  // load this row's x (BHWC gather; coalesced across lanes per c)
  const float* xb = xin + (size_t)b * (CDIM * HW) + hw;
  float x[CDIM];
#pragma unroll
  for (int c = 0; c < CDIM; ++c) x[c] = xb[c * HW];

  const float S = np_sumsq64(x);   // bit-matches np.sum(x*x, axis=1)

  float dmin = INFINITY;
  int   kmin = 0;

  for (int cb = 0; cb < NUM_K; cb += CHUNK) {
    __syncthreads();
    // stage 128 codes (32 KB) into LDS, coalesced float4
    const float4* gsrc = (const float4*)(emb + (size_t)cb * CDIM);
    float4* ldst = (float4*)e_s;
#pragma unroll
    for (int i = 0; i < (CHUNK * CDIM / 4) / 256; ++i)
      ldst[t + 256 * i] = gsrc[t + 256 * i];
    if (t < CHUNK) nk_s[t] = norms[cb + t];
    __syncthreads();

    // thread covers k = cb + 4*m + p, m ascending; 4 independent chains
    for (int jj = 0; jj < 32; jj += 4) {
      const int kk0 = 4 * jj + p;
      const float4* e0 = (const float4*)(e_s + (kk0 + 0) * CDIM);
      const float4* e1 = (const float4*)(e_s + (kk0 + 4) * CDIM);
      const float4* e2 = (const float4*)(e_s + (kk0 + 8) * CDIM);
      const float4* e3 = (const float4*)(e_s + (kk0 + 12) * CDIM);
      float d0 = 0.f, d1 = 0.f, d2 = 0.f, d3 = 0.f;
#pragma unroll
      for (int c4 = 0; c4 < 16; ++c4) {
        const float4 a0 = e0[c4]; const float4 a1 = e1[c4];
        const float4 a2 = e2[c4]; const float4 a3 = e3[c4];
        const float x0 = x[4*c4+0], x1 = x[4*c4+1], x2 = x[4*c4+2], x3 = x[4*c4+3];
        d0 = fmaf(x0, a0.x, d0); d1 = fmaf(x0, a1.x, d1);
        d2 = fmaf(x0, a2.x, d2); d3 = fmaf(x0, a3.x, d3);
        d0 = fmaf(x1, a0.y, d0); d1 = fmaf(x1, a1.y, d1);
        d2 = fmaf(x1, a2.y, d2); d3 = fmaf(x1, a3.y, d3);
        d0 = fmaf(x2, a0.z, d0); d1 = fmaf(x2, a1.z, d1);
        d2 = fmaf(x2, a2.z, d2); d3 = fmaf(x2, a3.z, d3);
        d0 = fmaf(x3, a0.w, d0); d1 = fmaf(x3, a1.w, d1);
        d2 = fmaf(x3, a2.w, d2); d3 = fmaf(x3, a3.w, d3);
      }
      // d = fl(fl(S - 2*dot) + n_k); 2*dot exact so FMA contraction is bit-identical
      const float q0 = (S - 2.0f * d0) + nk_s[kk0 + 0];
      const float q1 = (S - 2.0f * d1) + nk_s[kk0 + 4];
      const float q2 = (S - 2.0f * d2) + nk_s[kk0 + 8];
      const float q3 = (S - 2.0f * d3) + nk_s[kk0 + 12];
      const int kg = cb + kk0;
      if (q0 < dmin) { dmin = q0; kmin = kg; }
      if (q1 < dmin) { dmin = q1; kmin = kg + 4; }
      if (q2 < dmin) { dmin = q2; kmin = kg + 8; }
      if (q3 < dmin) { dmin = q3; kmin = kg + 12; }
    }
  }

  // lexicographic (d, k) combine across the 4 k-parities = np first-min semantics
  if (p != 0) {
    dmin_s[(p - 1) * RPB + r] = dmin;
    kmin_s[(p - 1) * RPB + r] = kmin;
  }
  __syncthreads();
  if (p == 0) {
#pragma unroll
    for (int q = 0; q < 3; ++q) {
      const float dq = dmin_s[q * RPB + r];
      const int   kq = kmin_s[q * RPB + r];
      if (dq < dmin || (dq == dmin && kq < kmin)) { dmin = dq; kmin = kq; }
    }
    out_idx[n] = (float)kmin;
    atomicAdd(&hist_s[kmin], 1u);

    // epilogue: quantized_st = fl(x + fl(q - x)); loss partial
    const float4* eb = (const float4*)(emb + (size_t)kmin * CDIM);
    float4* o = (float4*)(out0 + (size_t)n * CDIM);
    float ssq = 0.f;
#pragma unroll
    for (int c4 = 0; c4 < 16; ++c4) {
      const float4 q4 = eb[c4];
      const float x0 = x[4*c4+0], x1 = x[4*c4+1], x2 = x[4*c4+2], x3 = x[4*c4+3];
      const float u0 = q4.x - x0, u1 = q4.y - x1, u2 = q4.z - x2, u3 = q4.w - x3;
      ssq = fmaf(u0, u0, fmaf(u1, u1, fmaf(u2, u2, fmaf(u3, u3, ssq))));
      o[c4] = make_float4(x0 + u0, x1 + u1, x2 + u2, x3 + u3);
    }
#pragma unroll
    for (int off = 32; off > 0; off >>= 1) ssq += __shfl_down(ssq, off, 64);
    if (r == 0) partials[blockIdx.x] = (double)ssq;   // deterministic, no FP atomics
  }
  __syncthreads();
  for (int i = t; i < NUM_K; i += 256) {
    const unsigned int v = hist_s[i];
    if (v) atomicAdd(&counts[i], v);
  }
}

__global__ void vq_final(const double* __restrict__ partials,
                         const unsigned int* __restrict__ counts,
                         float* __restrict__ out_loss, float* __restrict__ out_perp)
{
  __shared__ double sh[256];
  const int t = threadIdx.x;
  double acc = 0.0, ent = 0.0;
  for (int i = t; i < NBLK; i += 256) acc += partials[i];
  for (int k = t; k < NUM_K; k += 256) {
    const double pr = (double)counts[k] * (1.0 / 65536.0);
    ent += pr * log(pr + 1e-10);
  }
  sh[t] = acc;
  __syncthreads();
  for (int s = 128; s > 0; s >>= 1) { if (t < s) sh[t] += sh[t + s]; __syncthreads(); }
  const double total = sh[0];
  __syncthreads();
  sh[t] = ent;
  __syncthreads();
  for (int s = 128; s > 0; s >>= 1) { if (t < s) sh[t] += sh[t + s]; __syncthreads(); }
  if (t == 0) {
    // vq_loss = mean((q-x)^2) * (1 + 0.25); means over N*C = 4194304 elements
    out_loss[0] = (float)(1.25 * total / 4194304.0);
    out_perp[0] = (float)exp(-sh[0]);
  }
}

extern "C" void kernel_launch(void* const* d_in, const int* in_sizes, int n_in,
                              void* d_out, int out_size, void* d_ws, size_t ws_size,
                              hipStream_t stream)
{
  const float* xin = (const float*)d_in[0];
  const float* emb = (const float*)d_in[1];
  float* out = (float*)d_out;

  // ws layout: [0,4K) fp32 norms[1024] | [4K,8K) u32 counts[1024] | [8K,16K) f64 partials[1024]
  float*        norms    = (float*)d_ws;
  unsigned int* counts   = (unsigned int*)((char*)d_ws + 4096);
  double*       partials = (double*)((char*)d_ws + 8192);

  hipMemsetAsync((char*)d_ws + 4096, 0, 4096, stream);  // zero counts only

  vq_norms<<<dim3(4), dim3(256), 0, stream>>>(emb, norms);

  float* out0     = out;                       // 4194304 elements (BHWC flat)
  float* out_loss = out + 4194304;             // scalar
  float* out_idx  = out + 4194305;             // 65536 elements (as float)
  float* out_perp = out + 4194305 + 65536;     // scalar

  vq_main<<<dim3(NBLK), dim3(256), 0, stream>>>(xin, emb, norms, out0, out_idx,
                                                partials, counts);
  vq_final<<<dim3(1), dim3(256), 0, stream>>>(partials, counts, out_loss, out_perp);
}